// Round 12
// baseline (332.699 us; speedup 1.0000x reference)
//
#include <hip/hip_runtime.h>
#include <cstdint>
#include <cstddef>

// ---------------------------------------------------------------------------
// GCN: 3 layers.  out = A_hat @ (h @ W) + b, A_hat = D^-1/2 (A+I) D^-1/2
// R11: GEMM epilogue pre-scales t by dinv[row] (t' = t*dinv), so aggregation
//      is an unweighted row-sum: y = (sum t'[src] + t'[node])*dinv[dst] + b.
//      agg inner loop uses fp16 pairwise pk_add tree (3.5 VALU/edge).
//      GEMM: BM=128/512thr/8 waves, A 3-deep + B 2-deep counted vmcnt.
// ---------------------------------------------------------------------------

static inline int cdiv_i(long a, long b) { return (int)((a + b - 1) / b); }

using half2v = __attribute__((ext_vector_type(2))) _Float16;
using half8 = __attribute__((ext_vector_type(8))) _Float16;
using f32x4 = __attribute__((ext_vector_type(4))) float;

__device__ __forceinline__ void gload_lds16(const void* g, void* l) {
    __builtin_amdgcn_global_load_lds(
        (const __attribute__((address_space(1))) unsigned int*)g,
        (__attribute__((address_space(3))) unsigned int*)l, 16, 0, 0);
}

template <int N>
__device__ __forceinline__ void wait_vmcnt() {
    if constexpr (N == 0) asm volatile("s_waitcnt vmcnt(0)" ::: "memory");
    else if constexpr (N == 1) asm volatile("s_waitcnt vmcnt(1)" ::: "memory");
    else asm volatile("s_waitcnt vmcnt(2)" ::: "memory");
}

__global__ void detect_fmt_kernel(const unsigned int* __restrict__ raw, int n_nodes,
                                  int* __restrict__ flag) {
    if (blockIdx.x == 0 && threadIdx.x == 0) {
        int is64 = 1;
        for (int i = 0; i < 64; ++i) {
            unsigned lo = raw[2 * i], hi = raw[2 * i + 1];
            if (hi != 0u || lo >= (unsigned)n_nodes) { is64 = 0; break; }
        }
        *flag = is64;
    }
}

__global__ void zero_i32_kernel(int* __restrict__ p, int n) {
    for (long i = blockIdx.x * (long)blockDim.x + threadIdx.x; i < n;
         i += (long)gridDim.x * blockDim.x)
        p[i] = 0;
}

// histogram of dst straight from the raw edge buffer
__global__ void hist_kernel(const void* __restrict__ raw, int* __restrict__ cnt,
                            int E, const int* __restrict__ flag) {
    const int f = *flag;
    for (long i = blockIdx.x * (long)blockDim.x + threadIdx.x; i < E;
         i += (long)gridDim.x * blockDim.x) {
        const int d = f ? (int)(((const long long*)raw)[E + i])
                        : ((const int*)raw)[E + i];
        atomicAdd(&cnt[d], 1);
    }
}

__global__ void dinv_kernel(const int* __restrict__ cnt, float* __restrict__ dinv, int n) {
    for (long i = blockIdx.x * (long)blockDim.x + threadIdx.x; i < n;
         i += (long)gridDim.x * blockDim.x)
        dinv[i] = rsqrtf((float)cnt[i] + 1.0f);  // +1 self-loop
}

// ---- exclusive scan over n ints: 1024 elems / block ----
__global__ __launch_bounds__(256) void scan1_kernel(const int* __restrict__ in,
                                                    int* __restrict__ out,
                                                    int* __restrict__ bsum, int n) {
    __shared__ int tsum[256];
    const int tid = threadIdx.x;
    const long base = (long)blockIdx.x * 1024 + (long)tid * 4;
    int v[4];
#pragma unroll
    for (int i = 0; i < 4; ++i) v[i] = (base + i < n) ? in[base + i] : 0;
    const int s = v[0] + v[1] + v[2] + v[3];
    tsum[tid] = s;
    __syncthreads();
    for (int off = 1; off < 256; off <<= 1) {
        int add = (tid >= off) ? tsum[tid - off] : 0;
        __syncthreads();
        tsum[tid] += add;
        __syncthreads();
    }
    int run = tsum[tid] - s;
#pragma unroll
    for (int i = 0; i < 4; ++i) {
        if (base + i < n) out[base + i] = run;
        run += v[i];
    }
    if (tid == 255) bsum[blockIdx.x] = tsum[255];
}

__global__ void scan2_kernel(int* __restrict__ bsum, int nb) {
    __shared__ int lds[256];
    const int tid = threadIdx.x;
    int v = (tid < nb) ? bsum[tid] : 0;
    lds[tid] = v;
    __syncthreads();
    for (int off = 1; off < 256; off <<= 1) {
        int add = (tid >= off) ? lds[tid - off] : 0;
        __syncthreads();
        lds[tid] += add;
        __syncthreads();
    }
    if (tid < nb) bsum[tid] = lds[tid] - v;
}

__global__ __launch_bounds__(256) void scan3_kernel(int* __restrict__ out,
                                                    const int* __restrict__ bsum, int n) {
    const long base = (long)blockIdx.x * 1024 + (long)threadIdx.x * 4;
    const int add = bsum[blockIdx.x];
#pragma unroll
    for (int i = 0; i < 4; ++i)
        if (base + i < n) out[base + i] += add;
}

__global__ void set_int_kernel(int* __restrict__ p, int idx, int val) {
    if (blockIdx.x == 0 && threadIdx.x == 0) p[idx] = val;
}

// scatter src into CSR col straight from the raw edge buffer
__global__ void scatter_kernel(const void* __restrict__ raw,
                               const int* __restrict__ row_ptr, int* __restrict__ fill,
                               int* __restrict__ col, int E,
                               const int* __restrict__ flag) {
    const int f = *flag;
    for (long i = blockIdx.x * (long)blockDim.x + threadIdx.x; i < E;
         i += (long)gridDim.x * blockDim.x) {
        int s, d;
        if (f) {
            s = (int)(((const long long*)raw)[i]);
            d = (int)(((const long long*)raw)[E + i]);
        } else {
            s = ((const int*)raw)[i];
            d = ((const int*)raw)[E + i];
        }
        int p = row_ptr[d] + atomicAdd(&fill[d], 1);
        col[p] = s;
    }
}

__device__ __forceinline__ void split8f(const float v[8], half8& hi, half8& lo) {
#pragma unroll
    for (int j = 0; j < 8; ++j) {
        _Float16 h = (_Float16)v[j];
        hi[j] = h;
        lo[j] = (_Float16)((v[j] - (float)h) * 4096.0f);
    }
}

// ---------------------------------------------------------------------------
// Pack W (fp32 [K][Nn]) into fragment-major fp16 hi/lo.
// Per (nt, ks) chunk: [split(2)][colgrp(BN/16)][lane(64)][8 halfs]
// lane l -> col = nt*BN + cg*16 + (l&15), k = ks*32 + (l>>4)*8 + j
// ---------------------------------------------------------------------------
__global__ void pack_w_kernel(const float* __restrict__ W, _Float16* __restrict__ P,
                              int K, int Nn, int BN, int total) {
    int id = blockIdx.x * 256 + threadIdx.x;
    if (id >= total) return;
    const int CG = BN / 16, KS = K >> 5;
    const int l = id & 63;
    int r = id >> 6;
    const int cg = r % CG; r /= CG;
    const int ks = r % KS;
    const int nt = r / KS;
    const int c = nt * BN + cg * 16 + (l & 15);
    const int kb = ks * 32 + (l >> 4) * 8;
    const size_t CHUNK = (size_t)2 * CG * 64 * 8;
    _Float16* base = P + (size_t)(nt * KS + ks) * CHUNK + (size_t)(cg * 64 + l) * 8;
    float v[8];
#pragma unroll
    for (int j = 0; j < 8; ++j) v[j] = W[(size_t)(kb + j) * Nn + c];
    half8 hi, lo;
    split8f(v, hi, lo);
    *(half8*)base = hi;
    *(half8*)(base + CHUNK / 2) = lo;
}

// ---------------------------------------------------------------------------
// Ch[M,Nn](fp16) = (A[M,K] @ Bpacked) * dinv[row], fp16 MFMA (A hi-only,
// B hi+lo).  BM=128, BN in {128,64}, BK=32, 512 threads = 8 waves.
// A staged coalesced row-major with XOR-swizzled 16B chunks (source-side),
// fragment ds_reads apply the same XOR. A 3-deep (HBM), B 2-deep (L2),
// counted vmcnt -- never drained to 0 mid-loop.
// ---------------------------------------------------------------------------
template <int BN, int AF16>
__global__ __launch_bounds__(512) void gemm_mfma_kernel(
    const void* __restrict__ Araw, const _Float16* __restrict__ Bp,
    _Float16* __restrict__ Ch, int M, int K, int Nn,
    const float* __restrict__ zbuf, const float* __restrict__ dinv) {
    constexpr int WC = BN / 64;              // wave cols: 2 or 1
    constexpr int WR = 8 / WC;               // wave rows: 4 or 8
    constexpr int MI = 128 / (WR * 16);      // 2 or 1
    constexpr int NI = 4;
    constexpr int BCH = 2 * (BN / 16) * 64 * 8;  // halfs per B stage
    constexpr int BBYTES = BCH * 2;          // 16 KB or 8 KB
    constexpr int BU = BBYTES / 8192;        // B loads per thread (2 or 1)
    constexpr int AL = AF16 ? 1 : 2;         // A loads per thread
    constexpr int ABYTES = AF16 ? 8192 : 16384;
    constexpr int PIPEB = 3 * ABYTES + 2 * BBYTES;
    constexpr int EPIB = 128 * BN * 2;
    constexpr int SMB = (PIPEB > EPIB) ? PIPEB : EPIB;

    __shared__ __align__(16) char smraw[SMB];
    char* bufA0 = smraw;
    char* bufB0 = smraw + 3 * ABYTES;

    const int tid = threadIdx.x;
    const int lane = tid & 63;
    const int wid = __builtin_amdgcn_readfirstlane(tid >> 6);   // 0..7
    const int wr = wid / WC, wc = wid % WC;
    const int bm = blockIdx.y * 128, bn = blockIdx.x * BN;
    const int KS = K >> 5;
    const _Float16* bchunk = Bp + (size_t)blockIdx.x * KS * BCH;

    // ---- A stage source addressing (coalesced + chunk-swizzled) ----
    const float* a32s0 = nullptr;
    const float* a32s1 = nullptr;
    const _Float16* a16s = nullptr;
    if constexpr (AF16) {
        const _Float16* A16 = (const _Float16*)Araw;
        const int rl = wid * 16 + (lane >> 2);           // local row 0..127
        const int kc = (lane & 3) ^ ((rl >> 1) & 3);     // swizzled 16B chunk
        const int gm = bm + rl;
        a16s = (gm < M) ? (A16 + (size_t)gm * K + kc * 8)
                        : (const _Float16*)zbuf;
    } else {
        const float* A32 = (const float*)Araw;
        const int rl0 = wid * 16 + (lane >> 3);          // rows 0..127 (j=0)
        const int rl1 = rl0 + 8;                         // j=1
        const int kc0 = (lane & 7) ^ (rl0 & 7);
        const int kc1 = (lane & 7) ^ (rl1 & 7);
        const int gm0 = bm + rl0, gm1 = bm + rl1;
        a32s0 = (gm0 < M) ? (A32 + (size_t)gm0 * K + kc0 * 4) : zbuf;
        a32s1 = (gm1 < M) ? (A32 + (size_t)gm1 * K + kc1 * 4) : zbuf;
    }

    f32x4 acc1[MI][NI] = {};
    f32x4 acc2[MI][NI] = {};

    auto stageA = [&](int b, int ks) {
        char* sA = bufA0 + b * ABYTES;
        if constexpr (AF16) {
            gload_lds16(a16s + ks * 32, sA + wid * 1024);
        } else {
            gload_lds16(a32s0 + ks * 32, sA + (wid * 2 + 0) * 1024);
            gload_lds16(a32s1 + ks * 32, sA + (wid * 2 + 1) * 1024);
        }
    };
    auto stageB = [&](int b, int ks) {
        char* sB = bufB0 + b * BBYTES;
        const _Float16* bc = bchunk + (size_t)ks * BCH;
#pragma unroll
        for (int rr = 0; rr < BU; ++rr)
            gload_lds16(bc + (size_t)(((wid * BU + rr) * 64 + lane) << 3),
                        sB + ((wid * BU + rr) << 10));
    };

    // ---- fragment read addresses (per-thread invariant) ----
    int aoff0[MI], aoff1[MI];  // byte offsets within an A buffer
#pragma unroll
    for (int mi = 0; mi < MI; ++mi) {
        const int r = (wr * MI + mi) * 16 + (lane & 15);
        if constexpr (AF16) {
            const int c = r * 4 + ((lane >> 4) ^ ((r >> 1) & 3));
            aoff0[mi] = c * 16;
            aoff1[mi] = 0;
        } else {
            const int g0 = (lane >> 4) * 2;
            const int sw = r & 7;
            aoff0[mi] = (r * 8 + (g0 ^ sw)) * 16;
            aoff1[mi] = (r * 8 + ((g0 + 1) ^ sw)) * 16;
        }
    }

    // prologue: A(0), B(0), A(1) -- FIFO order matters for counted waits
    stageA(0, 0);
    stageB(0, 0);
    if (1 < KS) stageA(1, 1);

    for (int ks = 0; ks < KS; ++ks) {
        if (ks + 1 < KS) wait_vmcnt<AL>();  // A(ks), B(ks) landed; A(ks+1) flying
        else wait_vmcnt<0>();
        __builtin_amdgcn_s_barrier();
        if (ks + 1 < KS) stageB((ks + 1) & 1, ks + 1);
        if (ks + 2 < KS) stageA((ks + 2) % 3, ks + 2);

        const char* cA = bufA0 + (ks % 3) * ABYTES;
        const _Float16* smB = (const _Float16*)(bufB0 + (ks & 1) * BBYTES);

        half8 afh[MI];
        if constexpr (AF16) {
#pragma unroll
            for (int mi = 0; mi < MI; ++mi)
                afh[mi] = *(const half8*)(cA + aoff0[mi]);
        } else {
#pragma unroll
            for (int mi = 0; mi < MI; ++mi) {
                f32x4 vlo = *(const f32x4*)(cA + aoff0[mi]);
                f32x4 vhi = *(const f32x4*)(cA + aoff1[mi]);
                half8 h;
                h[0] = (_Float16)vlo[0]; h[1] = (_Float16)vlo[1];
                h[2] = (_Float16)vlo[2]; h[3] = (_Float16)vlo[3];
                h[4] = (_Float16)vhi[0]; h[5] = (_Float16)vhi[1];
                h[6] = (_Float16)vhi[2]; h[7] = (_Float16)vhi[3];
                afh[mi] = h;
            }
        }
#pragma unroll
        for (int ni = 0; ni < NI; ++ni) {
            const half8 bh = *(const half8*)(smB + (((wc * 4 + ni) * 64 + lane) << 3));
            const half8 bl = *(const half8*)(smB + BCH / 2 + (((wc * 4 + ni) * 64 + lane) << 3));
#pragma unroll
            for (int mi = 0; mi < MI; ++mi) {
                acc1[mi][ni] = __builtin_amdgcn_mfma_f32_16x16x32_f16(
                    afh[mi], bh, acc1[mi][ni], 0, 0, 0);
                acc2[mi][ni] = __builtin_amdgcn_mfma_f32_16x16x32_f16(
                    afh[mi], bl, acc2[mi][ni], 0, 0, 0);
            }
        }
    }

    // ---- epilogue: scale by dinv[row], stage fp16 tile, coalesced store ----
    __syncthreads();
    _Float16* smC = (_Float16*)smraw;
    const float inv = 1.0f / 4096.0f;
#pragma unroll
    for (int mi = 0; mi < MI; ++mi) {
        const int row0 = (wr * MI + mi) * 16 + ((lane >> 4) << 2);
        const f32x4 dv4 = *(const f32x4*)(dinv + bm + row0);  // ws-padded, safe
#pragma unroll
        for (int ni = 0; ni < NI; ++ni) {
            const int colx = wc * 64 + ni * 16 + (lane & 15);
#pragma unroll
            for (int i = 0; i < 4; ++i) {
                const float dv = dv4[i];
                smC[(row0 + i) * BN + colx] =
                    (_Float16)fmaf(acc2[mi][ni][i], inv * dv,
                                   acc1[mi][ni][i] * dv);
            }
        }
    }
    __syncthreads();
    constexpr int UPR = BN / 8;               // 16B units per row
    constexpr int EPU = (128 * BN / 8) / 512; // units per thread (4 or 2)
#pragma unroll
    for (int r = 0; r < EPU; ++r) {
        const int u = r * 512 + tid;
        const int row = u / UPR, cu = u % UPR;
        const int grow = bm + row;
        if (grow < M)
            *(uint4*)(Ch + (size_t)grow * Nn + bn + cu * 8) =
                *(const uint4*)(smC + row * BN + cu * 8);
    }
}

__device__ __forceinline__ float elu1(float v) { return v > 0.f ? v : expm1f(v); }

// Pull aggregation over pre-scaled fp16 t' (Hdim=256): one wave per node,
// 32 lanes x half8 per row, 2 edges per wave-iteration, 4-pair unroll.
// fp16 pairwise tree (pk_add) + fp32 flush per 8-edge chunk.
// y = elu((sum + t'[node]) * dinv[node] + b [+ res]), y fp16.
template <int MODE>
__global__ __launch_bounds__(256) void agg_pull_kernel(
    const int* __restrict__ row_ptr, const int* __restrict__ col,
    const float* __restrict__ dinv, const _Float16* __restrict__ t,
    const float* __restrict__ bias, const _Float16* __restrict__ res,
    _Float16* __restrict__ y, int Nn, int Hdim) {
    const int node = blockIdx.x * (blockDim.x >> 6) + (threadIdx.x >> 6);
    if (node >= Nn) return;
    const int lane = threadIdx.x & 63;
    const int sub = lane >> 5;         // which edge of the pair
    const int f = (lane & 31) * 8;     // feature base (32 lanes x 8 = 256)

    float acc[8] = {0.f, 0.f, 0.f, 0.f, 0.f, 0.f, 0.f, 0.f};

    const int s0 = row_ptr[node], s1 = row_ptr[node + 1];
    int e = s0 + sub;
    for (; e + 7 < s1; e += 8) {
        int ss[4];
        half8 v[4];
#pragma unroll
        for (int u = 0; u < 4; ++u) ss[u] = col[e + 2 * u];
#pragma unroll
        for (int u = 0; u < 4; ++u)
            v[u] = *(const half8*)(t + (size_t)ss[u] * Hdim + f);
        const half8 sum = (v[0] + v[1]) + (v[2] + v[3]);  // v_pk_add_f16 tree
#pragma unroll
        for (int i = 0; i < 8; ++i) acc[i] += (float)sum[i];
    }
    for (; e < s1; e += 2) {
        const half8 v = *(const half8*)(t + (size_t)col[e] * Hdim + f);
#pragma unroll
        for (int i = 0; i < 8; ++i) acc[i] += (float)v[i];
    }

#pragma unroll
    for (int i = 0; i < 8; ++i) acc[i] += __shfl_xor(acc[i], 32);

    if (sub == 0) {
        const float dn = dinv[node];
        const half8 tn = *(const half8*)(t + (size_t)node * Hdim + f);
        float o[8];
#pragma unroll
        for (int i = 0; i < 8; ++i)
            o[i] = (acc[i] + (float)tn[i]) * dn + bias[f + i];
        if (MODE == 1) {
            const half8 rv = *(const half8*)(res + (size_t)node * Hdim + f);
#pragma unroll
            for (int i = 0; i < 8; ++i) o[i] += (float)rv[i];
        }
        half8 ov;
#pragma unroll
        for (int i = 0; i < 8; ++i) ov[i] = (_Float16)elu1(o[i]);
        *(half8*)(y + (size_t)node * Hdim + f) = ov;
    }
}

// Layer-3 aggregation over pre-scaled t' (Cdim=64): one wave/node, 2 edges
// per iteration (lane>>5), 4-pair unroll, fp16 tree, cross-half shfl reduce.
// y = (sum + t'[node]) * dinv[node] + b  (fp32 out).
__global__ __launch_bounds__(256) void agg_pull64_kernel(
    const int* __restrict__ row_ptr, const int* __restrict__ col,
    const float* __restrict__ dinv, const _Float16* __restrict__ t,
    const float* __restrict__ bias, float* __restrict__ y, int Nn) {
    const int node = blockIdx.x * (blockDim.x >> 6) + (threadIdx.x >> 6);
    if (node >= Nn) return;
    const int lane = threadIdx.x & 63;
    const int sub = lane >> 5;
    const int f = (lane & 31) * 2;

    float acc0 = 0.f, acc1 = 0.f;
    const int s0 = row_ptr[node], s1 = row_ptr[node + 1];
    int e = s0 + sub;
    for (; e + 7 < s1; e += 8) {
        half2v v[4];
#pragma unroll
        for (int u = 0; u < 4; ++u)
            v[u] = *(const half2v*)(t + (size_t)col[e + 2 * u] * 64 + f);
        const half2v s = (v[0] + v[1]) + (v[2] + v[3]);
        acc0 += (float)s[0];
        acc1 += (float)s[1];
    }
    for (; e < s1; e += 2) {
        const half2v v = *(const half2v*)(t + (size_t)col[e] * 64 + f);
        acc0 += (float)v[0];
        acc1 += (float)v[1];
    }

    acc0 += __shfl_xor(acc0, 32);
    acc1 += __shfl_xor(acc1, 32);

    const float dn = dinv[node];
    const half2v tn = *(const half2v*)(t + (size_t)node * 64 + f);
    const float o0 = (acc0 + (float)tn[0]) * dn + bias[f];
    const float o1 = (acc1 + (float)tn[1]) * dn + bias[f + 1];

    if (lane < 32) {
        float2 ov = make_float2(o0, o1);
        *(float2*)(y + (size_t)node * 64 + f) = ov;
    }
}

extern "C" void kernel_launch(void* const* d_in, const int* in_sizes, int n_in,
                              void* d_out, int out_size, void* d_ws, size_t ws_size,
                              hipStream_t stream) {
    const float* x = (const float*)d_in[0];
    const void* ei_raw = d_in[1];
    const float* W1 = (const float*)d_in[2];
    const float* b1 = (const float*)d_in[3];
    const float* W2 = (const float*)d_in[4];
    const float* b2 = (const float*)d_in[5];
    const float* W3 = (const float*)d_in[6];
    const float* b3 = (const float*)d_in[7];
    float* out = (float*)d_out;

    const int H = in_sizes[3];       // 256
    const int F = in_sizes[2] / H;   // 512
    const int N = in_sizes[0] / F;   // 50000
    const int C = in_sizes[7];       // 64
    const int E = in_sizes[1] / 2;   // 800000
    const int Mt = cdiv_i(N, 128);   // 391 row tiles

    // workspace layout
    char* ws = (char*)d_ws;
    size_t off = 0;
    auto take = [&](size_t bytes) -> char* {
        char* p = ws + off;
        off += (bytes + 255) & ~(size_t)255;
        return p;
    };
    float* dinv = (float*)take((size_t)(N + 256) * 4);   // padded for f32x4 tail reads
    int* flag = (int*)take(4);
    float* zbuf = (float*)take(4096);                    // 4KB zero page
    _Float16* th = (_Float16*)take((size_t)N * H * 2);   // GEMM output t' (fp16)
    _Float16* h1 = (_Float16*)take((size_t)N * H * 2);   // fp16 activations
    _Float16* h2 = (_Float16*)take((size_t)N * H * 2);
    int* col = (int*)take((size_t)E * 4);
    int* cnt = (int*)take((size_t)N * 4);
    int* row_ptr = (int*)take((size_t)(N + 1) * 4);
    int* fill = (int*)take((size_t)N * 4);
    int* bsum = (int*)take(256 * 4);
    _Float16* pW1 = (_Float16*)take((size_t)F * H * 2 * 2);
    _Float16* pW2 = (_Float16*)take((size_t)H * H * 2 * 2);
    _Float16* pW3 = (_Float16*)take((size_t)H * C * 2 * 2);
    (void)ws_size; (void)n_in; (void)out_size;

    const int nScanBlk = cdiv_i(N, 1024);

    // ---- edges + degrees + CSR (+ zero page for GEMM OOB rows) ----
    detect_fmt_kernel<<<1, 64, 0, stream>>>((const unsigned*)ei_raw, N, flag);
    zero_i32_kernel<<<4, 256, 0, stream>>>((int*)zbuf, 1024);
    zero_i32_kernel<<<cdiv_i(N, 256), 256, 0, stream>>>(cnt, N);
    hist_kernel<<<cdiv_i(E, 256), 256, 0, stream>>>(ei_raw, cnt, E, flag);
    dinv_kernel<<<cdiv_i(N, 256), 256, 0, stream>>>(cnt, dinv, N);
    scan1_kernel<<<nScanBlk, 256, 0, stream>>>(cnt, row_ptr, bsum, N);
    scan2_kernel<<<1, 256, 0, stream>>>(bsum, nScanBlk);
    scan3_kernel<<<nScanBlk, 256, 0, stream>>>(row_ptr, bsum, N);
    set_int_kernel<<<1, 1, 0, stream>>>(row_ptr, N, E);
    zero_i32_kernel<<<cdiv_i(N, 256), 256, 0, stream>>>(fill, N);
    scatter_kernel<<<cdiv_i(E, 256), 256, 0, stream>>>(ei_raw, row_ptr, fill, col, E, flag);

    // ---- pack weights (fragment-major fp16 hi/lo) ----
    const int tot1 = (H / 128) * (F / 32) * (128 / 16) * 64;
    const int tot2 = (H / 128) * (H / 32) * (128 / 16) * 64;
    const int tot3 = (C / 64) * (H / 32) * (64 / 16) * 64;
    pack_w_kernel<<<cdiv_i(tot1, 256), 256, 0, stream>>>(W1, pW1, F, H, 128, tot1);
    pack_w_kernel<<<cdiv_i(tot2, 256), 256, 0, stream>>>(W2, pW2, H, H, 128, tot2);
    pack_w_kernel<<<cdiv_i(tot3, 256), 256, 0, stream>>>(W3, pW3, H, C, 64, tot3);

    const int aggGridH = cdiv_i(N, 4);

    // ---- layer 1: h1 = elu(A_hat @ (x @ W1) + b1)
    gemm_mfma_kernel<128, 0><<<dim3(H / 128, Mt), 512, 0, stream>>>(
        x, pW1, th, N, F, H, zbuf, dinv);
    agg_pull_kernel<0><<<aggGridH, 256, 0, stream>>>(row_ptr, col, dinv, th, b1,
                                                     nullptr, h1, N, H);

    // ---- layer 2: h2 = elu(A_hat @ (h1 @ W2) + b2 + h1)
    gemm_mfma_kernel<128, 1><<<dim3(H / 128, Mt), 512, 0, stream>>>(
        h1, pW2, th, N, H, H, zbuf, dinv);
    agg_pull_kernel<1><<<aggGridH, 256, 0, stream>>>(row_ptr, col, dinv, th, b2,
                                                     h1, h2, N, H);

    // ---- layer 3: out = A_hat @ (h2 @ W3) + b3
    gemm_mfma_kernel<64, 1><<<dim3(C / 64, Mt), 512, 0, stream>>>(
        h2, pW3, th, N, H, C, zbuf, dinv);
    agg_pull64_kernel<<<aggGridH, 256, 0, stream>>>(row_ptr, col, dinv, th, b3, out, N);
}